// Round 2
// baseline (380.800 us; speedup 1.0000x reference)
//
#include <hip/hip_runtime.h>
#include <math.h>

#define BSZ    256
#define GRID_N 49
#define LSTMH  512
#define CNN_C  2048
#define PROJ   512
#define KAUG   (CNN_C + LSTMH)   // 2560 augmented K: [cnn | lstm] vs [W_cnn | W_lstm]
#define BK     32
#define NTILES (KAUG / BK)       // 80
// LDS chunk swizzle: k-block kq of row r stored at chunk (kq ^ SWZ(r&15)).
// Keeps ds_read_b128 bank conflicts <= 2-way (free, m136).
#define SWZ(r) ((((r) & 3)) ^ (((r) >> 2) & 3))

typedef short bf16x8 __attribute__((ext_vector_type(8)));
typedef float f32x4  __attribute__((ext_vector_type(4)));

static __device__ __forceinline__ unsigned short bf16_rne(float f) {
    unsigned int u = __float_as_uint(f);
    u = u + 0x7FFFu + ((u >> 16) & 1u);
    return (unsigned short)(u >> 16);
}
static __device__ __forceinline__ float bf16_f32(unsigned short h) {
    return __uint_as_float(((unsigned int)h) << 16);
}
static __device__ __forceinline__ uint4 pack8(unsigned short h0, unsigned short h1,
                                              unsigned short h2, unsigned short h3,
                                              unsigned short h4, unsigned short h5,
                                              unsigned short h6, unsigned short h7) {
    uint4 o;
    o.x = (unsigned int)h0 | ((unsigned int)h1 << 16);
    o.y = (unsigned int)h2 | ((unsigned int)h3 << 16);
    o.z = (unsigned int)h4 | ((unsigned int)h5 << 16);
    o.w = (unsigned int)h6 | ((unsigned int)h7 << 16);
    return o;
}
static __device__ __forceinline__ float tanh_fast(float x) {
    float e = __expf(2.f * x);            // large |x| -> saturates to +-1 correctly
    return 1.f - 2.f / (e + 1.f);
}

// ---- Prep: W_aug (512 x 2560) fp32 -> bf16(RNE) into d_ws. 8 elems/thread. ----
__global__ __launch_bounds__(256) void prep_w(const float* __restrict__ Wc,
                                              const float* __restrict__ Wl,
                                              unsigned short* __restrict__ wsW) {
    int c  = blockIdx.x * 256 + threadIdx.x;   // chunk id; 512*320 chunks exactly
    int p  = c / 320;
    int kc = (c % 320) * 8;
    const float* src = (kc < CNN_C) ? (Wc + (size_t)p * CNN_C + kc)
                                    : (Wl + (size_t)p * LSTMH + (kc - CNN_C));
    float4 f0 = ((const float4*)src)[0];
    float4 f1 = ((const float4*)src)[1];
    uint4 o = pack8(bf16_rne(f0.x), bf16_rne(f0.y), bf16_rne(f0.z), bf16_rne(f0.w),
                    bf16_rne(f1.x), bf16_rne(f1.y), bf16_rne(f1.z), bf16_rne(f1.w));
    *(uint4*)(wsW + (size_t)p * KAUG + kc) = o;
}

// ---- Main: one block per batch b. 512 threads = 8 waves. ----
// acc[g][p] = sum_k Aaug[g][k]*Waug[p][k]; A split hi+lo bf16 (exact-ish), W bf16-hi.
// Epilogue: z[b][g] = sum_p tanh(acc + b_lstm[p] + b_cnn[p]) * w_attn[p],
// written scrambled out[g*BSZ + b]; softmax kernel normalizes rows of (BSZ, GRID_N).
template <bool WS>
__global__ __launch_bounds__(512) void main_k(
    const float* __restrict__ lstm, const float* __restrict__ cnn,
    const float* __restrict__ Wc,   const float* __restrict__ Wl,
    const float* __restrict__ bl,   const float* __restrict__ bc,
    const float* __restrict__ wat,  const unsigned short* __restrict__ wsW,
    float* __restrict__ out)
{
    __shared__ unsigned short Ahi[64][BK];    // 4 KB   rows 49..63 = zero pad
    __shared__ unsigned short Alo[64][BK];    // 4 KB
    __shared__ unsigned short Bsh[PROJ][BK];  // 32 KB  W-hi tile
    __shared__ float zp[8][64];               // 2 KB   per-wave partial z

    const int b = blockIdx.x;
    const int t = threadIdx.x;
    const int l   = t & 63;
    const int w   = t >> 6;          // wave id: owns cols [64w, 64w+64)
    const int q   = l >> 4;          // quad
    const int r16 = l & 15;
    const int eff = q ^ SWZ(r16);    // swizzled read chunk (same for A and B rows: row&15==r16)
    const int koff = eff * 8;

    // staging roles
    const int sW  = SWZ(t & 15);     // B row p = t
    const int ar  = t >> 2;          // A row (t<196)
    const int seg = t & 3;           // A k-chunk
    const int sA  = SWZ(ar & 15);

    f32x4 acc[4][4];
    #pragma unroll
    for (int mt = 0; mt < 4; ++mt)
        #pragma unroll
        for (int nt = 0; nt < 4; ++nt)
            acc[mt][nt] = (f32x4){0.f, 0.f, 0.f, 0.f};

    // staging registers
    uint4  br[4];                    // WS path: bf16 W chunks
    float4 wr[8];                    // fallback: fp32 W
    float4 a0, a1;                   // A fp32 (8 elems)

    // ---- prologue: zero A pad rows once; load+store tile 0 ----
    if (t < 60) {
        int rr = 49 + (t >> 2), sg = t & 3;
        uint4 z = {0u, 0u, 0u, 0u};
        *(uint4*)&Ahi[rr][sg * 8] = z;
        *(uint4*)&Alo[rr][sg * 8] = z;
    }
    {
        const int k0 = 0;
        if constexpr (WS) {
            const uint4* s = (const uint4*)(wsW + (size_t)t * KAUG + k0);
            br[0] = s[0]; br[1] = s[1]; br[2] = s[2]; br[3] = s[3];
        } else {
            const float* s = Wc + (size_t)t * CNN_C + k0;
            #pragma unroll
            for (int i = 0; i < 8; ++i) wr[i] = ((const float4*)s)[i];
        }
        if (t < 196) {
            const float* s = cnn + ((size_t)b * GRID_N + ar) * CNN_C + k0 + seg * 8;
            a0 = ((const float4*)s)[0]; a1 = ((const float4*)s)[1];
        }
        // store tile 0
        if constexpr (WS) {
            #pragma unroll
            for (int c = 0; c < 4; ++c) *(uint4*)&Bsh[t][(c ^ sW) * 8] = br[c];
        } else {
            #pragma unroll
            for (int c = 0; c < 4; ++c) {
                float4 f0 = wr[2 * c], f1 = wr[2 * c + 1];
                *(uint4*)&Bsh[t][(c ^ sW) * 8] =
                    pack8(bf16_rne(f0.x), bf16_rne(f0.y), bf16_rne(f0.z), bf16_rne(f0.w),
                          bf16_rne(f1.x), bf16_rne(f1.y), bf16_rne(f1.z), bf16_rne(f1.w));
            }
        }
        if (t < 196) {
            unsigned short h[8];
            float f[8] = {a0.x, a0.y, a0.z, a0.w, a1.x, a1.y, a1.z, a1.w};
            unsigned short lo[8];
            #pragma unroll
            for (int i = 0; i < 8; ++i) {
                h[i]  = bf16_rne(f[i]);
                lo[i] = bf16_rne(f[i] - bf16_f32(h[i]));
            }
            *(uint4*)&Ahi[ar][(seg ^ sA) * 8] = pack8(h[0],h[1],h[2],h[3],h[4],h[5],h[6],h[7]);
            *(uint4*)&Alo[ar][(seg ^ sA) * 8] = pack8(lo[0],lo[1],lo[2],lo[3],lo[4],lo[5],lo[6],lo[7]);
        }
    }
    __syncthreads();

    // ---- K loop: 80 tiles, register prefetch, 2 barriers/tile (race-free by construction) ----
    for (int kt = 0; kt < NTILES; ++kt) {
        const bool more = (kt + 1 < NTILES);
        if (more) {
            const int k0 = (kt + 1) * BK;
            if constexpr (WS) {
                const uint4* s = (const uint4*)(wsW + (size_t)t * KAUG + k0);
                br[0] = s[0]; br[1] = s[1]; br[2] = s[2]; br[3] = s[3];
            } else {
                const float* s = (k0 < CNN_C) ? Wc + (size_t)t * CNN_C + k0
                                              : Wl + (size_t)t * LSTMH + (k0 - CNN_C);
                #pragma unroll
                for (int i = 0; i < 8; ++i) wr[i] = ((const float4*)s)[i];
            }
            if (t < 196) {
                const float* s = (k0 < CNN_C)
                    ? cnn + ((size_t)b * GRID_N + ar) * CNN_C + k0 + seg * 8
                    : lstm + (size_t)b * LSTMH + (k0 - CNN_C) + seg * 8;  // same for all rows
                a0 = ((const float4*)s)[0]; a1 = ((const float4*)s)[1];
            }
        }

        // compute on resident tile
        {
            bf16x8 ah[4], al[4], bh[4];
            #pragma unroll
            for (int mt = 0; mt < 4; ++mt) {
                const int row = mt * 16 + r16;
                ah[mt] = *(const bf16x8*)&Ahi[row][koff];
                al[mt] = *(const bf16x8*)&Alo[row][koff];
            }
            #pragma unroll
            for (int nt = 0; nt < 4; ++nt)
                bh[nt] = *(const bf16x8*)&Bsh[w * 64 + nt * 16 + r16][koff];
            #pragma unroll
            for (int mt = 0; mt < 4; ++mt)
                #pragma unroll
                for (int nt = 0; nt < 4; ++nt) {
                    acc[mt][nt] = __builtin_amdgcn_mfma_f32_16x16x32_bf16(
                        ah[mt], bh[nt], acc[mt][nt], 0, 0, 0);
                    acc[mt][nt] = __builtin_amdgcn_mfma_f32_16x16x32_bf16(
                        al[mt], bh[nt], acc[mt][nt], 0, 0, 0);
                }
        }
        __syncthreads();   // all reads of tile kt complete

        if (more) {
            if constexpr (WS) {
                #pragma unroll
                for (int c = 0; c < 4; ++c) *(uint4*)&Bsh[t][(c ^ sW) * 8] = br[c];
            } else {
                #pragma unroll
                for (int c = 0; c < 4; ++c) {
                    float4 f0 = wr[2 * c], f1 = wr[2 * c + 1];
                    *(uint4*)&Bsh[t][(c ^ sW) * 8] =
                        pack8(bf16_rne(f0.x), bf16_rne(f0.y), bf16_rne(f0.z), bf16_rne(f0.w),
                              bf16_rne(f1.x), bf16_rne(f1.y), bf16_rne(f1.z), bf16_rne(f1.w));
                }
            }
            if (t < 196) {
                float f[8] = {a0.x, a0.y, a0.z, a0.w, a1.x, a1.y, a1.z, a1.w};
                unsigned short h[8], lo[8];
                #pragma unroll
                for (int i = 0; i < 8; ++i) {
                    h[i]  = bf16_rne(f[i]);
                    lo[i] = bf16_rne(f[i] - bf16_f32(h[i]));
                }
                *(uint4*)&Ahi[ar][(seg ^ sA) * 8] = pack8(h[0],h[1],h[2],h[3],h[4],h[5],h[6],h[7]);
                *(uint4*)&Alo[ar][(seg ^ sA) * 8] = pack8(lo[0],lo[1],lo[2],lo[3],lo[4],lo[5],lo[6],lo[7]);
            }
        }
        __syncthreads();   // tile kt+1 visible
    }

    // ---- epilogue: tanh + w_attn dot, reduce cols ----
    // C/D layout (m89): D row m = q*4+reg (+16*mt), col n = r16 (+16*nt +64*w)
    float vs[4][4];
    #pragma unroll
    for (int mt = 0; mt < 4; ++mt)
        #pragma unroll
        for (int rr = 0; rr < 4; ++rr) vs[mt][rr] = 0.f;
    #pragma unroll
    for (int nt = 0; nt < 4; ++nt) {
        const int p = w * 64 + nt * 16 + r16;
        const float bb = bl[p] + bc[p];
        const float wa = wat[p];
        #pragma unroll
        for (int mt = 0; mt < 4; ++mt)
            #pragma unroll
            for (int rr = 0; rr < 4; ++rr)
                vs[mt][rr] += tanh_fast(acc[mt][nt][rr] + bb) * wa;
    }
    #pragma unroll
    for (int mt = 0; mt < 4; ++mt)
        #pragma unroll
        for (int rr = 0; rr < 4; ++rr) {
            float v = vs[mt][rr];
            v += __shfl_xor(v, 1);
            v += __shfl_xor(v, 2);
            v += __shfl_xor(v, 4);
            v += __shfl_xor(v, 8);           // sum over 16 cols within quad group
            if (r16 == 0) zp[w][mt * 16 + q * 4 + rr] = v;
        }
    __syncthreads();
    if (t < 64) {
        float z = 0.f;
        #pragma unroll
        for (int wv = 0; wv < 8; ++wv) z += zp[wv][t];
        if (t < GRID_N) out[t * BSZ + b] = z;   // scrambled position
    }
}

// Row softmax over 49 elements, in place. One wave per row.
__global__ __launch_bounds__(64) void softmax_rows(float* __restrict__ out)
{
    const int i = blockIdx.x;
    const int j = threadIdx.x;
    float x = (j < GRID_N) ? out[i * GRID_N + j] : -1e30f;
    float m = x;
    #pragma unroll
    for (int off = 32; off > 0; off >>= 1) m = fmaxf(m, __shfl_xor(m, off));
    float e = (j < GRID_N) ? __expf(x - m) : 0.f;
    float s = e;
    #pragma unroll
    for (int off = 32; off > 0; off >>= 1) s += __shfl_xor(s, off);
    if (j < GRID_N) out[i * GRID_N + j] = e / s;
}

extern "C" void kernel_launch(void* const* d_in, const int* in_sizes, int n_in,
                              void* d_out, int out_size, void* d_ws, size_t ws_size,
                              hipStream_t stream)
{
    const float* lstm = (const float*)d_in[0];
    const float* cnn  = (const float*)d_in[1];
    const float* Wl   = (const float*)d_in[2];
    const float* bl   = (const float*)d_in[3];
    const float* Wc   = (const float*)d_in[4];
    const float* bc   = (const float*)d_in[5];
    const float* wat  = (const float*)d_in[6];
    float* out = (float*)d_out;

    const size_t wneed = (size_t)PROJ * KAUG * sizeof(unsigned short);  // 2.62 MB
    if (ws_size >= wneed) {
        unsigned short* wsW = (unsigned short*)d_ws;
        prep_w<<<dim3(640), dim3(256), 0, stream>>>(Wc, Wl, wsW);
        main_k<true><<<dim3(BSZ), dim3(512), 0, stream>>>(lstm, cnn, Wc, Wl, bl, bc, wat, wsW, out);
    } else {
        main_k<false><<<dim3(BSZ), dim3(512), 0, stream>>>(lstm, cnn, Wc, Wl, bl, bc, wat, nullptr, out);
    }
    softmax_rows<<<dim3(BSZ), dim3(64), 0, stream>>>(out);
}

// Round 3
// 231.668 us; speedup vs baseline: 1.6437x; 1.6437x over previous
//
#include <hip/hip_runtime.h>
#include <math.h>

#define BSZ    256
#define GRID_N 49
#define LSTMH  512
#define CNN_C  2048
#define PROJ   512
#define KAUG   2560               // [cnn k=0..2047 | lstm k=2048..2559]
#define M_TOT  12544              // 256*49 = 196*64 exactly
#define MT     64
#define NT     256
#define BK     64
#define KTILES (KAUG / BK)        // 40
#define NBLK   ((M_TOT / MT) * (PROJ / NT))   // 392

typedef short bf16x8 __attribute__((ext_vector_type(8)));
typedef float f32x4  __attribute__((ext_vector_type(4)));

static __device__ __forceinline__ unsigned short bf16_rne(float f) {
    unsigned int u = __float_as_uint(f);
    u = u + 0x7FFFu + ((u >> 16) & 1u);
    return (unsigned short)(u >> 16);
}
static __device__ __forceinline__ uint4 pack8f(const float* f) {
    uint4 o;
    o.x = (unsigned int)bf16_rne(f[0]) | ((unsigned int)bf16_rne(f[1]) << 16);
    o.y = (unsigned int)bf16_rne(f[2]) | ((unsigned int)bf16_rne(f[3]) << 16);
    o.z = (unsigned int)bf16_rne(f[4]) | ((unsigned int)bf16_rne(f[5]) << 16);
    o.w = (unsigned int)bf16_rne(f[6]) | ((unsigned int)bf16_rne(f[7]) << 16);
    return o;
}
static __device__ __forceinline__ float tanh_fast(float x) {
    float e = __expf(2.f * x);
    return 1.f - 2.f / (e + 1.f);
}
// async 16B global->LDS (wave-uniform LDS base + lane*16)
static __device__ __forceinline__ void glds16(const void* g, void* l) {
    __builtin_amdgcn_global_load_lds(
        (const __attribute__((address_space(1))) unsigned int*)g,
        (__attribute__((address_space(3))) unsigned int*)l, 16, 0, 0);
}

// ---- Prep: W_aug (512 x 2560) fp32 -> bf16(RNE) into d_ws (proven in r2) ----
__global__ __launch_bounds__(256) void prep_w(const float* __restrict__ Wc,
                                              const float* __restrict__ Wl,
                                              unsigned short* __restrict__ wsW) {
    int c  = blockIdx.x * 256 + threadIdx.x;   // 512*320 chunks exactly
    int p  = c / 320;
    int kc = (c % 320) * 8;
    const float* src = (kc < CNN_C) ? (Wc + (size_t)p * CNN_C + kc)
                                    : (Wl + (size_t)p * LSTMH + (kc - CNN_C));
    float f[8];
    *(float4*)&f[0] = ((const float4*)src)[0];
    *(float4*)&f[4] = ((const float4*)src)[1];
    *(uint4*)(wsW + (size_t)p * KAUG + kc) = pack8f(f);
}

// ---- Main GEMM: tile MT x NT, A = [cnn|lstm] rows (bf16-hi), B = W_aug bf16.
// Epilogue: partial_z(row) = sum_{p in tile} tanh(acc + bias[p]) * w_attn[p],
// atomicAdd into out[g*BSZ + b] (scrambled layout). out pre-zeroed by memset.
template <bool WS>
__global__ __launch_bounds__(256, 2) void gemm_k(
    const float* __restrict__ lstm, const float* __restrict__ cnn,
    const float* __restrict__ Wc,   const float* __restrict__ Wl,
    const float* __restrict__ bl,   const float* __restrict__ bc,
    const float* __restrict__ wat,  const unsigned short* __restrict__ wsW,
    float* __restrict__ out)
{
    __shared__ unsigned short Ash[MT][BK];   // 8 KB
    __shared__ unsigned short Bsh[NT][BK];   // 32 KB
    __shared__ float zp[4][MT];              // 1 KB

    const int t   = threadIdx.x;
    const int w   = t >> 6;
    const int l   = t & 63;
    const int q   = l >> 4;
    const int r16 = l & 15;

    const int m0 = (int)(blockIdx.x >> 1) * MT;
    const int n0 = (int)(blockIdx.x & 1) * NT;

    // A staging identity: thread t owns row ra, chunks {ca0, ca0+4} (8 floats each)
    const int ra  = t >> 2;
    const int ca0 = t & 3;
    const int sa  = ra & 7;
    const int grow = m0 + ra;
    const int ab   = grow / 49;
    const int ag   = grow - ab * 49;
    const float* cnnb  = cnn + ((size_t)ab * GRID_N + ag) * CNN_C;
    const float* lstmb = lstm + (size_t)ab * LSTMH;

    f32x4 acc[4][4];
    #pragma unroll
    for (int mt = 0; mt < 4; ++mt)
        #pragma unroll
        for (int nt = 0; nt < 4; ++nt)
            acc[mt][nt] = (f32x4){0.f, 0.f, 0.f, 0.f};

    float4 fa0, fa1, fa2, fa3;   // A prefetch (chunk ca0 -> fa0/fa1, ca0+4 -> fa2/fa3)

    auto a_load = [&](int k0) {
        const float* s = (k0 < CNN_C) ? (cnnb + k0) : (lstmb + (k0 - CNN_C));
        const float4* p0 = (const float4*)(s + ca0 * 8);
        const float4* p1 = (const float4*)(s + (ca0 + 4) * 8);
        fa0 = p0[0]; fa1 = p0[1];
        fa2 = p1[0]; fa3 = p1[1];
    };
    auto a_write = [&]() {
        float f[8];
        *(float4*)&f[0] = fa0; *(float4*)&f[4] = fa1;
        *(uint4*)&Ash[ra][(ca0 ^ sa) * 8] = pack8f(f);
        *(float4*)&f[0] = fa2; *(float4*)&f[4] = fa3;
        *(uint4*)&Ash[ra][((ca0 + 4) ^ sa) * 8] = pack8f(f);
    };
    auto b_stage = [&](int k0) {
        if constexpr (WS) {
            // glds: per wave-instr 8 rows x 8 chunks; swizzle folded into source addr
            const int rsub = l >> 3;            // 0..7 (== local_row & 7)
            const int cg   = (l & 7) ^ rsub;    // source chunk for store pos l&7
            #pragma unroll
            for (int j = 0; j < 8; ++j) {
                const int rowb = w * 64 + j * 8;
                const unsigned short* g =
                    wsW + (size_t)(n0 + rowb + rsub) * KAUG + k0 + cg * 8;
                glds16(g, &Bsh[rowb][0]);
            }
        } else {
            // fallback: convert fp32 W in-kernel; thread t owns row t
            const float* s = (k0 < CNN_C) ? (Wc + (size_t)(n0 + t) * CNN_C + k0)
                                          : (Wl + (size_t)(n0 + t) * LSTMH + (k0 - CNN_C));
            const int sw = t & 7;
            #pragma unroll
            for (int c = 0; c < 8; ++c) {
                float f[8];
                *(float4*)&f[0] = ((const float4*)(s + c * 8))[0];
                *(float4*)&f[4] = ((const float4*)(s + c * 8))[1];
                *(uint4*)&Bsh[t][(c ^ sw) * 8] = pack8f(f);
            }
        }
    };

    // prologue: stage tile 0
    a_load(0);
    a_write();
    b_stage(0);

    for (int kt = 0; kt < KTILES; ++kt) {
        __syncthreads();                      // tile kt visible (drains vmcnt too)
        const bool more = (kt + 1 < KTILES);
        if (more) a_load((kt + 1) * BK);      // global->reg prefetch overlaps compute
        // compute on tile kt
        #pragma unroll
        for (int ks = 0; ks < 2; ++ks) {
            const int cp = ((ks * 4 + q) ^ (r16 & 7)) * 8;
            bf16x8 af[4], bfr[4];
            #pragma unroll
            for (int mt = 0; mt < 4; ++mt)
                af[mt] = *(const bf16x8*)&Ash[mt * 16 + r16][cp];
            #pragma unroll
            for (int nt = 0; nt < 4; ++nt)
                bfr[nt] = *(const bf16x8*)&Bsh[w * 64 + nt * 16 + r16][cp];
            #pragma unroll
            for (int mt = 0; mt < 4; ++mt)
                #pragma unroll
                for (int nt = 0; nt < 4; ++nt)
                    acc[mt][nt] = __builtin_amdgcn_mfma_f32_16x16x32_bf16(
                        af[mt], bfr[nt], acc[mt][nt], 0, 0, 0);
        }
        __syncthreads();                      // reads of tile kt done
        if (more) { a_write(); b_stage((kt + 1) * BK); }
    }

    // ---- epilogue: tanh + w_attn partial dot over this block's 256 cols ----
    float part[4][4];
    #pragma unroll
    for (int mt = 0; mt < 4; ++mt)
        #pragma unroll
        for (int rr = 0; rr < 4; ++rr) part[mt][rr] = 0.f;
    #pragma unroll
    for (int nt = 0; nt < 4; ++nt) {
        const int p = n0 + w * 64 + nt * 16 + r16;
        const float bb = bl[p] + bc[p];
        const float wa = wat[p];
        #pragma unroll
        for (int mt = 0; mt < 4; ++mt)
            #pragma unroll
            for (int rr = 0; rr < 4; ++rr)
                part[mt][rr] += tanh_fast(acc[mt][nt][rr] + bb) * wa;
    }
    #pragma unroll
    for (int mt = 0; mt < 4; ++mt)
        #pragma unroll
        for (int rr = 0; rr < 4; ++rr) {
            float v = part[mt][rr];
            v += __shfl_xor(v, 1);
            v += __shfl_xor(v, 2);
            v += __shfl_xor(v, 4);
            v += __shfl_xor(v, 8);            // sum over 16 cols (r16 group)
            if (r16 == 0) zp[w][mt * 16 + q * 4 + rr] = v;
        }
    __syncthreads();
    if (t < MT) {
        const float v = zp[0][t] + zp[1][t] + zp[2][t] + zp[3][t];
        const int row = m0 + t;
        const int b2  = row / 49;
        const int g2  = row - b2 * 49;
        atomicAdd(&out[g2 * BSZ + b2], v);    // scrambled position
    }
}

// Row softmax over 49 elements, in place. One wave per row.
__global__ __launch_bounds__(64) void softmax_rows(float* __restrict__ out)
{
    const int i = blockIdx.x;
    const int j = threadIdx.x;
    float x = (j < GRID_N) ? out[i * GRID_N + j] : -1e30f;
    float m = x;
    #pragma unroll
    for (int off = 32; off > 0; off >>= 1) m = fmaxf(m, __shfl_xor(m, off));
    float e = (j < GRID_N) ? __expf(x - m) : 0.f;
    float s = e;
    #pragma unroll
    for (int off = 32; off > 0; off >>= 1) s += __shfl_xor(s, off);
    if (j < GRID_N) out[i * GRID_N + j] = e / s;
}

extern "C" void kernel_launch(void* const* d_in, const int* in_sizes, int n_in,
                              void* d_out, int out_size, void* d_ws, size_t ws_size,
                              hipStream_t stream)
{
    const float* lstm = (const float*)d_in[0];
    const float* cnn  = (const float*)d_in[1];
    const float* Wl   = (const float*)d_in[2];
    const float* bl   = (const float*)d_in[3];
    const float* Wc   = (const float*)d_in[4];
    const float* bc   = (const float*)d_in[5];
    const float* wat  = (const float*)d_in[6];
    float* out = (float*)d_out;

    hipMemsetAsync(out, 0, (size_t)out_size * sizeof(float), stream);

    const size_t wneed = (size_t)PROJ * KAUG * sizeof(unsigned short);  // 2.62 MB
    if (ws_size >= wneed) {
        unsigned short* wsW = (unsigned short*)d_ws;
        prep_w<<<dim3(640), dim3(256), 0, stream>>>(Wc, Wl, wsW);
        gemm_k<true><<<dim3(NBLK), dim3(256), 0, stream>>>(lstm, cnn, Wc, Wl, bl, bc, wat, wsW, out);
    } else {
        gemm_k<false><<<dim3(NBLK), dim3(256), 0, stream>>>(lstm, cnn, Wc, Wl, bl, bc, wat, nullptr, out);
    }
    softmax_rows<<<dim3(BSZ), dim3(64), 0, stream>>>(out);
}